// Round 6
// baseline (138.040 us; speedup 1.0000x reference)
//
#include <hip/hip_runtime.h>
#include <cstdint>

typedef __bf16 bf16_t;
typedef __bf16 bf16x4 __attribute__((ext_vector_type(4)));
typedef __bf16 bf16x8 __attribute__((ext_vector_type(8)));
typedef float f32x4 __attribute__((ext_vector_type(4)));
typedef float f32x16 __attribute__((ext_vector_type(16)));
typedef unsigned int u32x2 __attribute__((ext_vector_type(2)));
typedef unsigned int u32x4 __attribute__((ext_vector_type(4)));

#define B_ 4
#define C_ 256
#define N_ 4096
#define NH_ 4
#define HD_ 64

static __device__ __forceinline__ f32x4 mfma_bf16(bf16x8 a, bf16x8 b, f32x4 c) {
  return __builtin_amdgcn_mfma_f32_16x16x32_bf16(a, b, c, 0, 0, 0);
}

static __device__ __forceinline__ f32x16 mfma32(bf16x8 a, bf16x8 b, f32x16 c) {
  return __builtin_amdgcn_mfma_f32_32x32x16_bf16(a, b, c, 0, 0, 0);
}

static __device__ __forceinline__ void async16(const void* g, void* l) {
  __builtin_amdgcn_global_load_lds(
      (__attribute__((address_space(1))) void*)(uintptr_t)g,
      (__attribute__((address_space(3))) void*)(uint32_t)(uintptr_t)l,
      16, 0, 0);
}

static __device__ __forceinline__ float fexp2(float x) {
#if __has_builtin(__builtin_amdgcn_exp2f)
  return __builtin_amdgcn_exp2f(x);  // raw v_exp_f32
#else
  return exp2f(x);
#endif
}

static __device__ __forceinline__ unsigned pack_bf16(float lo, float hi) {
  bf16x4 t;
  t[0] = (bf16_t)lo;
  t[1] = (bf16_t)hi;
  return *(unsigned*)&t;
}

// ---------------- kernel 1: GN stats -> per-(b,c) affine ----------------
__global__ __launch_bounds__(256) void k_gn_stats(const float* __restrict__ x,
                                                  const float* __restrict__ gn_w,
                                                  const float* __restrict__ gn_b,
                                                  float* __restrict__ gnscale,
                                                  float* __restrict__ gnshift) {
  const int bg = blockIdx.x;
  const int b = bg >> 5, g = bg & 31;
  const float4* p4 = (const float4*)(x + (size_t)(b * C_ + g * 8) * N_);
  float s = 0.f, ss = 0.f;
  for (int i = threadIdx.x; i < 8192; i += 256) {
    float4 v = p4[i];
    s += (v.x + v.y) + (v.z + v.w);
    ss += (v.x * v.x + v.y * v.y) + (v.z * v.z + v.w * v.w);
  }
  for (int off = 32; off > 0; off >>= 1) {
    s += __shfl_down(s, off);
    ss += __shfl_down(ss, off);
  }
  __shared__ float red_s[4], red_ss[4];
  const int wid = threadIdx.x >> 6, lane = threadIdx.x & 63;
  if (lane == 0) { red_s[wid] = s; red_ss[wid] = ss; }
  __syncthreads();
  if (threadIdx.x < 8) {
    float S = (red_s[0] + red_s[1]) + (red_s[2] + red_s[3]);
    float SS = (red_ss[0] + red_ss[1]) + (red_ss[2] + red_ss[3]);
    float mean = S * (1.f / 32768.f);
    float var = SS * (1.f / 32768.f) - mean * mean;
    float rstd = rsqrtf(var + 1e-5f);
    int c = g * 8 + threadIdx.x;
    float w = gn_w[c];
    gnscale[b * C_ + c] = w * rstd;
    gnshift[b * C_ + c] = gn_b[c] - mean * rstd * w;
  }
}

// ---------------- kernel 2: weight fp32 -> bf16 ----------------
__global__ __launch_bounds__(256) void k_conv_w(const float* __restrict__ qkv_w,
                                                const float* __restrict__ out_w,
                                                bf16_t* __restrict__ w1,
                                                bf16_t* __restrict__ w2) {
  int i = blockIdx.x * 256 + threadIdx.x;
  if (i < 3 * C_ * C_) w1[i] = (bf16_t)qkv_w[i];
  else w2[i - 3 * C_ * C_] = (bf16_t)out_w[i - 3 * C_ * C_];
}

// ---------------- kernel 3: GN apply + transpose ----------------
__global__ __launch_bounds__(256) void k_gn_apply(const float* __restrict__ x,
                                                  const float* __restrict__ gnscale,
                                                  const float* __restrict__ gnshift,
                                                  bf16_t* __restrict__ h) {
  const int chunk = blockIdx.x & 31;
  const int tok = (blockIdx.x >> 5) * 256 + threadIdx.x;
  const int b = tok >> 12, n = tok & (N_ - 1);
  const int c0 = chunk * 8;
  const float* xb = x + (size_t)(b * C_ + c0) * N_ + n;
  float sc[8], sh[8];
#pragma unroll
  for (int j = 0; j < 8; ++j) {
    sc[j] = gnscale[b * C_ + c0 + j];
    sh[j] = gnshift[b * C_ + c0 + j];
  }
  bf16x8 o;
#pragma unroll
  for (int j = 0; j < 8; ++j)
    o[j] = (bf16_t)(xb[(size_t)j * N_] * sc[j] + sh[j]);
  *(bf16x8*)(h + (size_t)tok * C_ + c0) = o;
}

// ---------------- kernel 4: QKV GEMM ----------------
__global__ __launch_bounds__(256) void k_gemm_qkv(const bf16_t* __restrict__ h,
                                                  const bf16_t* __restrict__ w1,
                                                  const float* __restrict__ qkv_b,
                                                  bf16_t* __restrict__ Qb,
                                                  bf16_t* __restrict__ Kb,
                                                  bf16_t* __restrict__ Vb) {
  __shared__ bf16_t As[128 * 32], Bs[128 * 32];
  const int tid = threadIdx.x, lane = tid & 63, wid = tid >> 6;
  const int g = lane >> 4, q = lane & 15;
  const int wm = wid >> 1, wn = wid & 1;
  const int m0 = blockIdx.x * 128;
  const int o0 = blockIdx.y * 128;
  f32x4 acc[4][4] = {};
  const int srow = lane >> 2, scol = (lane & 3) * 8;
  for (int kc = 0; kc < 8; ++kc) {
    const int k0 = kc * 32;
#pragma unroll
    for (int j = 0; j < 2; ++j) {
      const int chunk = wid + j * 4;
      async16(h + (size_t)(m0 + chunk * 16 + srow) * C_ + k0 + scol, &As[chunk * 512]);
      async16(w1 + (size_t)(o0 + chunk * 16 + srow) * C_ + k0 + scol, &Bs[chunk * 512]);
    }
    __syncthreads();
    bf16x8 a[4], bb[4];
#pragma unroll
    for (int t = 0; t < 4; ++t) {
      a[t] = *(const bf16x8*)&As[(wm * 64 + t * 16 + q) * 32 + g * 8];
      bb[t] = *(const bf16x8*)&Bs[(wn * 64 + t * 16 + q) * 32 + g * 8];
    }
#pragma unroll
    for (int mi = 0; mi < 4; ++mi)
#pragma unroll
      for (int ni = 0; ni < 4; ++ni)
        acc[mi][ni] = mfma_bf16(a[mi], bb[ni], acc[mi][ni]);
    __syncthreads();
  }
  const float QSCALE = 0.1803368801111244f;  // (1/sqrt(64)) * log2(e)
#pragma unroll
  for (int ni = 0; ni < 4; ++ni) {
    const int o = o0 + wn * 64 + ni * 16 + q;
    const float bias = qkv_b[o];
    const int mat = o >> 8;
    const int c = o & 255, hh = c >> 6, d = c & 63;
#pragma unroll
    for (int mi = 0; mi < 4; ++mi) {
      const int tokb = m0 + wm * 64 + mi * 16 + g * 4;
      const int b = tokb >> 12, n = tokb & (N_ - 1);
      const size_t bh = (size_t)(b * NH_ + hh);
      f32x4 t = acc[mi][ni] + bias;
      if (mat == 0) {
#pragma unroll
        for (int r = 0; r < 4; ++r)
          Qb[(bh * N_ + n + r) * HD_ + d] = (bf16_t)(t[r] * QSCALE);
      } else if (mat == 1) {
#pragma unroll
        for (int r = 0; r < 4; ++r)
          Kb[(bh * N_ + n + r) * HD_ + d] = (bf16_t)t[r];
      } else {
        *(bf16x4*)(Vb + (bh * HD_ + d) * N_ + n) = __builtin_convertvector(t, bf16x4);
      }
    }
  }
}

// ---------------- kernel 5: flash attention, 32x32x16 MFMA, no-max softmax ----------------
// 8 waves/block, 32 q/wave (q = lane&31; lanes q and q+32 hold complementary
// key-row halves). S^T = K*Q via 2 chains of 4 mfma32; P = exp2(S) directly;
// l = per-lane 32 adds + shfl_xor(32); P^T->B-frag via 4 packs + 2
// permlane32_swap per 16-key chunk; PV via 8 mfma32.
template <int SPLIT>
__global__ __launch_bounds__(512, 4) void k_attn(const bf16_t* __restrict__ Qb,
                                                 const bf16_t* __restrict__ Kb,
                                                 const bf16_t* __restrict__ Vb,
                                                 bf16_t* __restrict__ att,
                                                 bf16_t* __restrict__ Opart,
                                                 float* __restrict__ lsum) {
  __shared__ __align__(16) bf16_t Ks[2][4096];  // [buf][key(64)][d(64)]
  __shared__ __align__(16) bf16_t Vs[2][4096];  // [buf][d(64)][key(64)]
  const int tid = threadIdx.x, lane = tid & 63, wid = tid >> 6;  // wid 0..7
  const int l31 = lane & 31, hi = lane >> 5;
  const int r7 = l31 & 7;
  int bid = blockIdx.x;
  const int nb = 256 * SPLIT;
  bid = (bid & 7) * (nb / 8) + (bid >> 3);  // XCD-contiguous
  int bh, qt, kh;
  if (SPLIT == 2) { bh = bid >> 5; qt = (bid >> 1) & 15; kh = bid & 1; }
  else { bh = bid >> 4; qt = bid & 15; kh = 0; }
  const int nq0 = qt * 256 + wid * 32;
  const int k00 = kh * (N_ / SPLIT);
  const int NT = (N_ / SPLIT) / 64;
  const size_t base = (size_t)bh << 18;
  const bf16_t* Qp = Qb + base;
  const bf16_t* Kp = Kb + base;
  const bf16_t* Vp = Vb + base;

  // Q B-operand frags: col q = l31, k(d) = i*16 + hi*8 + j
  bf16x8 bq[4];
#pragma unroll
  for (int i = 0; i < 4; ++i)
    bq[i] = *(const bf16x8*)(Qp + (size_t)(nq0 + l31) * HD_ + i * 16 + hi * 8);

  const int srow = lane >> 3;
  const int sc16 = (lane & 7) ^ srow;

  f32x16 acc0 = {}, acc1 = {};
  float lacc = 0.f;

  // prologue: 8 waves each stage one 1KB K-chunk and one 1KB V-chunk
  async16(Kp + (size_t)(k00 + wid * 8 + srow) * HD_ + sc16 * 8, &Ks[0][wid * 512]);
  async16(Vp + (size_t)(wid * 8 + srow) * N_ + k00 + sc16 * 8, &Vs[0][wid * 512]);
  __syncthreads();

  const bf16_t* kS = Kp + (size_t)(k00 + 64 + wid * 8 + srow) * HD_ + sc16 * 8;
  const bf16_t* vS = Vp + (size_t)(wid * 8 + srow) * N_ + k00 + 64 + sc16 * 8;

  for (int t = 0; t < NT; ++t) {
    const int buf = t & 1;
    if (t < NT - 1) {
      async16(kS, &Ks[buf ^ 1][wid * 512]);
      async16(vS, &Vs[buf ^ 1][wid * 512]);
      kS += 64 * HD_;
      vS += 64;
    }
    const bf16_t* Kl = Ks[buf];
    const bf16_t* Vl = Vs[buf];
    // ---- QK^T: S^T[64k][32q], two 32x32 tiles ----
    f32x16 s0, s1;
    const f32x16 z = {};
    __builtin_amdgcn_s_setprio(1);
#pragma unroll
    for (int i = 0; i < 4; ++i) {
      bf16x8 k0 = *(const bf16x8*)(Kl + l31 * 64 + ((2 * i + hi) ^ r7) * 8);
      bf16x8 k1 = *(const bf16x8*)(Kl + (32 + l31) * 64 + ((2 * i + hi) ^ r7) * 8);
      if (i == 0) {
        s0 = mfma32(k0, bq[0], z);
        s1 = mfma32(k1, bq[0], z);
      } else {
        s0 = mfma32(k0, bq[i], s0);
        s1 = mfma32(k1, bq[i], s1);
      }
    }
    __builtin_amdgcn_s_setprio(0);
    // ---- P = exp2(s) (no max subtraction; bf16 P has f32 exponent range) ----
#pragma unroll
    for (int r = 0; r < 16; ++r) {
      s0[r] = fexp2(s0[r]);
      s1[r] = fexp2(s1[r]);
    }
    float lt0 = 0.f, lt1 = 0.f;
#pragma unroll
    for (int r = 0; r < 16; ++r) {
      lt0 += s0[r];
      lt1 += s1[r];
    }
    lacc += lt0 + lt1;
    // ---- transpose P^T -> B-operand frags (4 packs + 2 p32swaps per chunk) ----
    bf16x8 pb[4];
#pragma unroll
    for (int kc = 0; kc < 4; ++kc) {
      const int bs = (kc & 1) * 8;
      unsigned uA, uB, uC, uD;
      if (kc < 2) {
        uA = pack_bf16(s0[bs + 0], s0[bs + 1]);
        uB = pack_bf16(s0[bs + 2], s0[bs + 3]);
        uC = pack_bf16(s0[bs + 4], s0[bs + 5]);
        uD = pack_bf16(s0[bs + 6], s0[bs + 7]);
      } else {
        uA = pack_bf16(s1[bs + 0], s1[bs + 1]);
        uB = pack_bf16(s1[bs + 2], s1[bs + 3]);
        uC = pack_bf16(s1[bs + 4], s1[bs + 5]);
        uD = pack_bf16(s1[bs + 6], s1[bs + 7]);
      }
      u32x4 w;
#if __has_builtin(__builtin_amdgcn_permlane32_swap)
      u32x2 sAC = __builtin_amdgcn_permlane32_swap(uA, uC, false, false);
      u32x2 sBD = __builtin_amdgcn_permlane32_swap(uB, uD, false, false);
      w[0] = sAC[0]; w[1] = sBD[0]; w[2] = sAC[1]; w[3] = sBD[1];
#else
      w[0] = (hi == 0) ? uA : (unsigned)__shfl((int)uC, l31);
      w[1] = (hi == 0) ? uB : (unsigned)__shfl((int)uD, l31);
      w[2] = (hi == 0) ? (unsigned)__shfl((int)uA, l31 + 32) : uC;
      w[3] = (hi == 0) ? (unsigned)__shfl((int)uB, l31 + 32) : uD;
#endif
      pb[kc] = *(bf16x8*)&w;
    }
    // ---- PV: O^T[d][q] += V^T * P^T ----
    __builtin_amdgcn_s_setprio(1);
#pragma unroll
    for (int kc = 0; kc < 4; ++kc) {
      bf16x8 v0 = *(const bf16x8*)(Vl + l31 * 64 + ((2 * kc + hi) ^ r7) * 8);
      bf16x8 v1 = *(const bf16x8*)(Vl + (32 + l31) * 64 + ((2 * kc + hi) ^ r7) * 8);
      acc0 = mfma32(v0, pb[kc], acc0);
      acc1 = mfma32(v1, pb[kc], acc1);
    }
    __builtin_amdgcn_s_setprio(0);
    __syncthreads();
  }

  lacc += __shfl_xor(lacc, 32);

  if (SPLIT == 1) {
    const float inv = 1.0f / lacc;
    const int b = bh >> 2, hh = bh & 3;
    bf16_t* op = att + ((size_t)b * N_ + nq0 + l31) * C_ + hh * HD_;
#pragma unroll
    for (int dt = 0; dt < 2; ++dt) {
      const f32x16& a = dt ? acc1 : acc0;
#pragma unroll
      for (int qd = 0; qd < 4; ++qd) {
        bf16x4 r;
#pragma unroll
        for (int m = 0; m < 4; ++m) r[m] = (bf16_t)(a[qd * 4 + m] * inv);
        *(bf16x4*)(op + dt * 32 + qd * 8 + hi * 4) = r;
      }
    }
  } else {
    bf16_t* op = Opart + ((size_t)(kh * 16 + bh) * N_ + nq0 + l31) * HD_;
#pragma unroll
    for (int dt = 0; dt < 2; ++dt) {
      const f32x16& a = dt ? acc1 : acc0;
#pragma unroll
      for (int qd = 0; qd < 4; ++qd) {
        bf16x4 r;
#pragma unroll
        for (int m = 0; m < 4; ++m) r[m] = (bf16_t)a[qd * 4 + m];
        *(bf16x4*)(op + dt * 32 + qd * 8 + hi * 4) = r;
      }
    }
    if (hi == 0) {
      const size_t mlb = (size_t)(kh * 16 + bh) * N_;
      lsum[mlb + nq0 + l31] = lacc;
    }
  }
}

// ---------------- kernel 5b: combine the two key-halves ----------------
__global__ __launch_bounds__(256) void k_attn_combine(const bf16_t* __restrict__ Opart,
                                                      const float* __restrict__ lsum,
                                                      bf16_t* __restrict__ att) {
  const int gid = blockIdx.x * 256 + threadIdx.x;  // 524288
  const int d8 = gid & 7;
  const int q = (gid >> 3) & (N_ - 1);
  const int bh = gid >> 15;
  const float l1 = lsum[(size_t)bh * N_ + q];
  const float l2 = lsum[(size_t)(16 + bh) * N_ + q];
  const float inv = 1.0f / (l1 + l2);
  const bf16x8 o1 = *(const bf16x8*)(Opart + ((size_t)bh * N_ + q) * HD_ + d8 * 8);
  const bf16x8 o2 = *(const bf16x8*)(Opart + ((size_t)(16 + bh) * N_ + q) * HD_ + d8 * 8);
  bf16x8 r;
#pragma unroll
  for (int j = 0; j < 8; ++j)
    r[j] = (bf16_t)(((float)o1[j] + (float)o2[j]) * inv);
  const int b = bh >> 2, hh = bh & 3;
  *(bf16x8*)(att + ((size_t)b * N_ + q) * C_ + hh * HD_ + d8 * 8) = r;
}

// ---------------- kernel 6: out-proj GEMM + bias + residual ----------------
__global__ __launch_bounds__(256) void k_gemm_out(const bf16_t* __restrict__ att,
                                                  const bf16_t* __restrict__ w2,
                                                  const float* __restrict__ out_b,
                                                  const float* __restrict__ x,
                                                  float* __restrict__ out) {
  __shared__ bf16_t As[128 * 32], Bs[128 * 32];
  const int tid = threadIdx.x, lane = tid & 63, wid = tid >> 6;
  const int g = lane >> 4, q = lane & 15;
  const int wm = wid >> 1, wn = wid & 1;
  const int m0 = blockIdx.x * 128;
  const int o0 = blockIdx.y * 128;
  f32x4 acc[4][4] = {};
  const int srow = lane >> 2, scol = (lane & 3) * 8;
  for (int kc = 0; kc < 8; ++kc) {
    const int k0 = kc * 32;
#pragma unroll
    for (int j = 0; j < 2; ++j) {
      const int chunk = wid + j * 4;
      async16(att + (size_t)(m0 + chunk * 16 + srow) * C_ + k0 + scol, &As[chunk * 512]);
      async16(w2 + (size_t)(o0 + chunk * 16 + srow) * C_ + k0 + scol, &Bs[chunk * 512]);
    }
    __syncthreads();
    bf16x8 a[4], bb[4];
#pragma unroll
    for (int t = 0; t < 4; ++t) {
      a[t] = *(const bf16x8*)&As[(wm * 64 + t * 16 + q) * 32 + g * 8];
      bb[t] = *(const bf16x8*)&Bs[(wn * 64 + t * 16 + q) * 32 + g * 8];
    }
#pragma unroll
    for (int mi = 0; mi < 4; ++mi)
#pragma unroll
      for (int ni = 0; ni < 4; ++ni)
        acc[mi][ni] = mfma_bf16(a[mi], bb[ni], acc[mi][ni]);
    __syncthreads();
  }
#pragma unroll
  for (int ni = 0; ni < 4; ++ni) {
    const int o = o0 + wn * 64 + ni * 16 + q;
    const float bias = out_b[o];
#pragma unroll
    for (int mi = 0; mi < 4; ++mi) {
      const int tokb = m0 + wm * 64 + mi * 16 + g * 4;
      const int b = tokb >> 12, n = tokb & (N_ - 1);
      const size_t idx = ((size_t)(b * C_ + o) << 12) + n;
      const float4 xv = *(const float4*)(x + idx);
      f32x4 t = acc[mi][ni];
      float4 r = make_float4(t[0] + bias + xv.x, t[1] + bias + xv.y,
                             t[2] + bias + xv.z, t[3] + bias + xv.w);
      *(float4*)(out + idx) = r;
    }
  }
}

extern "C" void kernel_launch(void* const* d_in, const int* in_sizes, int n_in,
                              void* d_out, int out_size, void* d_ws, size_t ws_size,
                              hipStream_t stream) {
  (void)in_sizes; (void)n_in; (void)out_size;
  const float* x = (const float*)d_in[0];
  const float* gn_w = (const float*)d_in[1];
  const float* gn_b = (const float*)d_in[2];
  const float* qkv_w = (const float*)d_in[3];
  const float* qkv_b = (const float*)d_in[4];
  const float* out_w = (const float*)d_in[5];
  const float* out_b = (const float*)d_in[6];
  float* out = (float*)d_out;

  char* ws = (char*)d_ws;
  float* gnscale = (float*)ws;            // 1024 f32
  float* gnshift = gnscale + 1024;        // 1024 f32
  bf16_t* w1bf = (bf16_t*)(ws + 8192);    // 196608 bf16
  bf16_t* w2bf = w1bf + 196608;           // 65536 bf16
  bf16_t* hbuf = w2bf + 65536;            // 4194304 bf16
  bf16_t* Qb = hbuf + 4194304;
  bf16_t* Kb = Qb + 4194304;
  bf16_t* Vb = Kb + 4194304;
  bf16_t* Opart = Vb + 4194304;           // 8388608 bf16 (split mode only)
  float* lsum = (float*)(Opart + 8388608);  // 131072 f32
  const size_t need = (size_t)((char*)(lsum + 131072) - ws);
  const bool split = ws_size >= need;

  k_gn_stats<<<128, 256, 0, stream>>>(x, gn_w, gn_b, gnscale, gnshift);
  k_conv_w<<<1024, 256, 0, stream>>>(qkv_w, out_w, w1bf, w2bf);
  k_gn_apply<<<2048, 256, 0, stream>>>(x, gnscale, gnshift, hbuf);
  k_gemm_qkv<<<dim3(128, 6), 256, 0, stream>>>(hbuf, w1bf, qkv_b, Qb, Kb, Vb);
  if (split) {
    k_attn<2><<<512, 512, 0, stream>>>(Qb, Kb, Vb, hbuf, Opart, lsum);
    k_attn_combine<<<2048, 256, 0, stream>>>(Opart, lsum, hbuf);
  } else {
    k_attn<1><<<256, 512, 0, stream>>>(Qb, Kb, Vb, hbuf, Opart, lsum);
  }
  k_gemm_out<<<dim3(128, 2), 256, 0, stream>>>(hbuf, w2bf, out_b, x, out);
}

// Round 7
// 132.865 us; speedup vs baseline: 1.0389x; 1.0389x over previous
//
#include <hip/hip_runtime.h>
#include <cstdint>

typedef __bf16 bf16_t;
typedef __bf16 bf16x4 __attribute__((ext_vector_type(4)));
typedef __bf16 bf16x8 __attribute__((ext_vector_type(8)));
typedef float f32x4 __attribute__((ext_vector_type(4)));
typedef float f32x16 __attribute__((ext_vector_type(16)));
typedef unsigned int u32x2 __attribute__((ext_vector_type(2)));
typedef unsigned int u32x4 __attribute__((ext_vector_type(4)));

#define B_ 4
#define C_ 256
#define N_ 4096
#define NH_ 4
#define HD_ 64

static __device__ __forceinline__ f32x4 mfma_bf16(bf16x8 a, bf16x8 b, f32x4 c) {
  return __builtin_amdgcn_mfma_f32_16x16x32_bf16(a, b, c, 0, 0, 0);
}

static __device__ __forceinline__ f32x16 mfma32(bf16x8 a, bf16x8 b, f32x16 c) {
  return __builtin_amdgcn_mfma_f32_32x32x16_bf16(a, b, c, 0, 0, 0);
}

static __device__ __forceinline__ void async16(const void* g, void* l) {
  __builtin_amdgcn_global_load_lds(
      (__attribute__((address_space(1))) void*)(uintptr_t)g,
      (__attribute__((address_space(3))) void*)(uint32_t)(uintptr_t)l,
      16, 0, 0);
}

static __device__ __forceinline__ float fexp2(float x) {
#if __has_builtin(__builtin_amdgcn_exp2f)
  return __builtin_amdgcn_exp2f(x);  // raw v_exp_f32
#else
  return exp2f(x);
#endif
}

static __device__ __forceinline__ unsigned pack_bf16(float lo, float hi) {
  bf16x4 t;
  t[0] = (bf16_t)lo;
  t[1] = (bf16_t)hi;
  return *(unsigned*)&t;
}

// ---------------- kernel 1: GN stats -> per-(b,c) affine ----------------
__global__ __launch_bounds__(256) void k_gn_stats(const float* __restrict__ x,
                                                  const float* __restrict__ gn_w,
                                                  const float* __restrict__ gn_b,
                                                  float* __restrict__ gnscale,
                                                  float* __restrict__ gnshift) {
  const int bg = blockIdx.x;
  const int b = bg >> 5, g = bg & 31;
  const float4* p4 = (const float4*)(x + (size_t)(b * C_ + g * 8) * N_);
  float s = 0.f, ss = 0.f;
  for (int i = threadIdx.x; i < 8192; i += 256) {
    float4 v = p4[i];
    s += (v.x + v.y) + (v.z + v.w);
    ss += (v.x * v.x + v.y * v.y) + (v.z * v.z + v.w * v.w);
  }
  for (int off = 32; off > 0; off >>= 1) {
    s += __shfl_down(s, off);
    ss += __shfl_down(ss, off);
  }
  __shared__ float red_s[4], red_ss[4];
  const int wid = threadIdx.x >> 6, lane = threadIdx.x & 63;
  if (lane == 0) { red_s[wid] = s; red_ss[wid] = ss; }
  __syncthreads();
  if (threadIdx.x < 8) {
    float S = (red_s[0] + red_s[1]) + (red_s[2] + red_s[3]);
    float SS = (red_ss[0] + red_ss[1]) + (red_ss[2] + red_ss[3]);
    float mean = S * (1.f / 32768.f);
    float var = SS * (1.f / 32768.f) - mean * mean;
    float rstd = rsqrtf(var + 1e-5f);
    int c = g * 8 + threadIdx.x;
    float w = gn_w[c];
    gnscale[b * C_ + c] = w * rstd;
    gnshift[b * C_ + c] = gn_b[c] - mean * rstd * w;
  }
}

// ---------------- kernel 2: weight fp32 -> bf16 ----------------
__global__ __launch_bounds__(256) void k_conv_w(const float* __restrict__ qkv_w,
                                                const float* __restrict__ out_w,
                                                bf16_t* __restrict__ w1,
                                                bf16_t* __restrict__ w2) {
  int i = blockIdx.x * 256 + threadIdx.x;
  if (i < 3 * C_ * C_) w1[i] = (bf16_t)qkv_w[i];
  else w2[i - 3 * C_ * C_] = (bf16_t)out_w[i - 3 * C_ * C_];
}

// ---------------- kernel 3: GN apply + transpose (LDS-coalesced) ----------------
// 512 blocks x 32 tokens. Phase 1: coalesced x reads (lane = token), affine,
// into LDS tile [32][258] (odd-dword stride -> conflict-free column writes).
// Phase 2: coalesced h writes (one 512B token row per wave per pass).
__global__ __launch_bounds__(256) void k_gn_apply(const float* __restrict__ x,
                                                  const float* __restrict__ gnscale,
                                                  const float* __restrict__ gnshift,
                                                  bf16_t* __restrict__ h) {
  __shared__ bf16_t T[32 * 258];
  const int t = threadIdx.x;
  const int tok0 = blockIdx.x * 32;
  const int b = tok0 >> 12;
  const int n0 = tok0 & (N_ - 1);
  const int nl = t & 31, cset = t >> 5;  // token lane, 32-channel set
  const float* xb = x + ((size_t)(b * C_ + cset * 32) << 12) + n0 + nl;
  const float* scp = gnscale + b * C_ + cset * 32;
  const float* shp = gnshift + b * C_ + cset * 32;
#pragma unroll
  for (int j = 0; j < 32; ++j) {
    float y = xb[(size_t)j << 12] * scp[j] + shp[j];
    T[nl * 258 + cset * 32 + j] = (bf16_t)y;
  }
  __syncthreads();
  // phase 2: 8 passes; each wave writes one token's 512B row
  const int c4 = t & 63;  // 4-channel chunk
#pragma unroll
  for (int p = 0; p < 8; ++p) {
    const int tokl = p * 4 + (t >> 6);
    const int idx = tokl * 258 + c4 * 4;  // even -> 4B aligned
    uint2 v;
    v.x = *(const unsigned*)&T[idx];
    v.y = *(const unsigned*)&T[idx + 2];
    *(uint2*)(h + ((size_t)(tok0 + tokl) << 8) + c4 * 4) = v;
  }
}

// ---------------- kernel 4: QKV GEMM ----------------
__global__ __launch_bounds__(256) void k_gemm_qkv(const bf16_t* __restrict__ h,
                                                  const bf16_t* __restrict__ w1,
                                                  const float* __restrict__ qkv_b,
                                                  bf16_t* __restrict__ Qb,
                                                  bf16_t* __restrict__ Kb,
                                                  bf16_t* __restrict__ Vb) {
  __shared__ bf16_t As[128 * 32], Bs[128 * 32];
  const int tid = threadIdx.x, lane = tid & 63, wid = tid >> 6;
  const int g = lane >> 4, q = lane & 15;
  const int wm = wid >> 1, wn = wid & 1;
  const int m0 = blockIdx.x * 128;
  const int o0 = blockIdx.y * 128;
  f32x4 acc[4][4] = {};
  const int srow = lane >> 2, scol = (lane & 3) * 8;
  for (int kc = 0; kc < 8; ++kc) {
    const int k0 = kc * 32;
#pragma unroll
    for (int j = 0; j < 2; ++j) {
      const int chunk = wid + j * 4;
      async16(h + (size_t)(m0 + chunk * 16 + srow) * C_ + k0 + scol, &As[chunk * 512]);
      async16(w1 + (size_t)(o0 + chunk * 16 + srow) * C_ + k0 + scol, &Bs[chunk * 512]);
    }
    __syncthreads();
    bf16x8 a[4], bb[4];
#pragma unroll
    for (int t = 0; t < 4; ++t) {
      a[t] = *(const bf16x8*)&As[(wm * 64 + t * 16 + q) * 32 + g * 8];
      bb[t] = *(const bf16x8*)&Bs[(wn * 64 + t * 16 + q) * 32 + g * 8];
    }
#pragma unroll
    for (int mi = 0; mi < 4; ++mi)
#pragma unroll
      for (int ni = 0; ni < 4; ++ni)
        acc[mi][ni] = mfma_bf16(a[mi], bb[ni], acc[mi][ni]);
    __syncthreads();
  }
  const float QSCALE = 0.1803368801111244f;  // (1/sqrt(64)) * log2(e)
#pragma unroll
  for (int ni = 0; ni < 4; ++ni) {
    const int o = o0 + wn * 64 + ni * 16 + q;
    const float bias = qkv_b[o];
    const int mat = o >> 8;
    const int c = o & 255, hh = c >> 6, d = c & 63;
#pragma unroll
    for (int mi = 0; mi < 4; ++mi) {
      const int tokb = m0 + wm * 64 + mi * 16 + g * 4;
      const int b = tokb >> 12, n = tokb & (N_ - 1);
      const size_t bh = (size_t)(b * NH_ + hh);
      f32x4 t = acc[mi][ni] + bias;
      if (mat == 0) {
#pragma unroll
        for (int r = 0; r < 4; ++r)
          Qb[(bh * N_ + n + r) * HD_ + d] = (bf16_t)(t[r] * QSCALE);
      } else if (mat == 1) {
#pragma unroll
        for (int r = 0; r < 4; ++r)
          Kb[(bh * N_ + n + r) * HD_ + d] = (bf16_t)t[r];
      } else {
        *(bf16x4*)(Vb + (bh * HD_ + d) * N_ + n) = __builtin_convertvector(t, bf16x4);
      }
    }
  }
}

// ---------------- kernel 5: flash attention, 32x32x16 MFMA, no-max softmax ----------------
// Swizzle key widened to (row&7)^(row>>3): lanes l,l+8,l+16,l+24 (same lane&7)
// now read 4 distinct LDS columns -> no concentrated 4-way bank conflict.
template <int SPLIT>
__global__ __launch_bounds__(512, 4) void k_attn(const bf16_t* __restrict__ Qb,
                                                 const bf16_t* __restrict__ Kb,
                                                 const bf16_t* __restrict__ Vb,
                                                 bf16_t* __restrict__ att,
                                                 bf16_t* __restrict__ Opart,
                                                 float* __restrict__ lsum) {
  __shared__ __align__(16) bf16_t Ks[2][4096];  // [buf][key(64)][d(64)]
  __shared__ __align__(16) bf16_t Vs[2][4096];  // [buf][d(64)][key(64)]
  const int tid = threadIdx.x, lane = tid & 63, wid = tid >> 6;  // wid 0..7
  const int l31 = lane & 31, hi = lane >> 5;
  const int r7 = l31 & 7;
  const int rk = r7 ^ (l31 >> 3);  // read-side swizzle key for rows 0..31
  int bid = blockIdx.x;
  const int nb = 256 * SPLIT;
  bid = (bid & 7) * (nb / 8) + (bid >> 3);  // XCD-contiguous
  int bh, qt, kh;
  if (SPLIT == 2) { bh = bid >> 5; qt = (bid >> 1) & 15; kh = bid & 1; }
  else { bh = bid >> 4; qt = bid & 15; kh = 0; }
  const int nq0 = qt * 256 + wid * 32;
  const int k00 = kh * (N_ / SPLIT);
  const int NT = (N_ / SPLIT) / 64;
  const size_t base = (size_t)bh << 18;
  const bf16_t* Qp = Qb + base;
  const bf16_t* Kp = Kb + base;
  const bf16_t* Vp = Vb + base;

  // Q B-operand frags: col q = l31, k(d) = i*16 + hi*8 + j
  bf16x8 bq[4];
#pragma unroll
  for (int i = 0; i < 4; ++i)
    bq[i] = *(const bf16x8*)(Qp + (size_t)(nq0 + l31) * HD_ + i * 16 + hi * 8);

  const int srow = lane >> 3;
  const int sc16 = ((lane & 7) ^ srow ^ wid) & 7;  // inverse-swizzled source chunk

  f32x16 acc0 = {}, acc1 = {};
  float lacc = 0.f;

  // prologue: 8 waves each stage one 1KB K-chunk and one 1KB V-chunk
  async16(Kp + (size_t)(k00 + wid * 8 + srow) * HD_ + sc16 * 8, &Ks[0][wid * 512]);
  async16(Vp + (size_t)(wid * 8 + srow) * N_ + k00 + sc16 * 8, &Vs[0][wid * 512]);
  __syncthreads();

  const bf16_t* kS = Kp + (size_t)(k00 + 64 + wid * 8 + srow) * HD_ + sc16 * 8;
  const bf16_t* vS = Vp + (size_t)(wid * 8 + srow) * N_ + k00 + 64 + sc16 * 8;

  for (int t = 0; t < NT; ++t) {
    const int buf = t & 1;
    if (t < NT - 1) {
      async16(kS, &Ks[buf ^ 1][wid * 512]);
      async16(vS, &Vs[buf ^ 1][wid * 512]);
      kS += 64 * HD_;
      vS += 64;
    }
    const bf16_t* Kl = Ks[buf];
    const bf16_t* Vl = Vs[buf];
    // ---- QK^T: S^T[64k][32q], two 32x32 tiles ----
    f32x16 s0, s1;
    const f32x16 z = {};
    __builtin_amdgcn_s_setprio(1);
#pragma unroll
    for (int i = 0; i < 4; ++i) {
      bf16x8 k0 = *(const bf16x8*)(Kl + l31 * 64 + ((((2 * i + hi) ^ rk) & 7) * 8));
      bf16x8 k1 = *(const bf16x8*)(Kl + (32 + l31) * 64 + ((((2 * i + hi) ^ rk ^ 4) & 7) * 8));
      if (i == 0) {
        s0 = mfma32(k0, bq[0], z);
        s1 = mfma32(k1, bq[0], z);
      } else {
        s0 = mfma32(k0, bq[i], s0);
        s1 = mfma32(k1, bq[i], s1);
      }
    }
    __builtin_amdgcn_s_setprio(0);
    // ---- P = exp2(s) (no max subtraction; bf16 P has f32 exponent range) ----
#pragma unroll
    for (int r = 0; r < 16; ++r) {
      s0[r] = fexp2(s0[r]);
      s1[r] = fexp2(s1[r]);
    }
    float lt0 = 0.f, lt1 = 0.f;
#pragma unroll
    for (int r = 0; r < 16; ++r) {
      lt0 += s0[r];
      lt1 += s1[r];
    }
    lacc += lt0 + lt1;
    // ---- transpose P^T -> B-operand frags (4 packs + 2 p32swaps per chunk) ----
    bf16x8 pb[4];
#pragma unroll
    for (int kc = 0; kc < 4; ++kc) {
      const int bs = (kc & 1) * 8;
      unsigned uA, uB, uC, uD;
      if (kc < 2) {
        uA = pack_bf16(s0[bs + 0], s0[bs + 1]);
        uB = pack_bf16(s0[bs + 2], s0[bs + 3]);
        uC = pack_bf16(s0[bs + 4], s0[bs + 5]);
        uD = pack_bf16(s0[bs + 6], s0[bs + 7]);
      } else {
        uA = pack_bf16(s1[bs + 0], s1[bs + 1]);
        uB = pack_bf16(s1[bs + 2], s1[bs + 3]);
        uC = pack_bf16(s1[bs + 4], s1[bs + 5]);
        uD = pack_bf16(s1[bs + 6], s1[bs + 7]);
      }
      u32x4 w;
#if __has_builtin(__builtin_amdgcn_permlane32_swap)
      u32x2 sAC = __builtin_amdgcn_permlane32_swap(uA, uC, false, false);
      u32x2 sBD = __builtin_amdgcn_permlane32_swap(uB, uD, false, false);
      w[0] = sAC[0]; w[1] = sBD[0]; w[2] = sAC[1]; w[3] = sBD[1];
#else
      w[0] = (hi == 0) ? uA : (unsigned)__shfl((int)uC, l31);
      w[1] = (hi == 0) ? uB : (unsigned)__shfl((int)uD, l31);
      w[2] = (hi == 0) ? (unsigned)__shfl((int)uA, l31 + 32) : uC;
      w[3] = (hi == 0) ? (unsigned)__shfl((int)uB, l31 + 32) : uD;
#endif
      pb[kc] = *(bf16x8*)&w;
    }
    // ---- PV: O^T[d][q] += V^T * P^T ----
    __builtin_amdgcn_s_setprio(1);
#pragma unroll
    for (int kc = 0; kc < 4; ++kc) {
      bf16x8 v0 = *(const bf16x8*)(Vl + l31 * 64 + ((((2 * kc + hi) ^ rk) & 7) * 8));
      bf16x8 v1 = *(const bf16x8*)(Vl + (32 + l31) * 64 + ((((2 * kc + hi) ^ rk ^ 4) & 7) * 8));
      acc0 = mfma32(v0, pb[kc], acc0);
      acc1 = mfma32(v1, pb[kc], acc1);
    }
    __builtin_amdgcn_s_setprio(0);
    __syncthreads();
  }

  lacc += __shfl_xor(lacc, 32);

  if (SPLIT == 1) {
    const float inv = 1.0f / lacc;
    const int b = bh >> 2, hh = bh & 3;
    bf16_t* op = att + ((size_t)b * N_ + nq0 + l31) * C_ + hh * HD_;
#pragma unroll
    for (int dt = 0; dt < 2; ++dt) {
      const f32x16& a = dt ? acc1 : acc0;
#pragma unroll
      for (int qd = 0; qd < 4; ++qd) {
        bf16x4 r;
#pragma unroll
        for (int m = 0; m < 4; ++m) r[m] = (bf16_t)(a[qd * 4 + m] * inv);
        *(bf16x4*)(op + dt * 32 + qd * 8 + hi * 4) = r;
      }
    }
  } else {
    bf16_t* op = Opart + ((size_t)(kh * 16 + bh) * N_ + nq0 + l31) * HD_;
#pragma unroll
    for (int dt = 0; dt < 2; ++dt) {
      const f32x16& a = dt ? acc1 : acc0;
#pragma unroll
      for (int qd = 0; qd < 4; ++qd) {
        bf16x4 r;
#pragma unroll
        for (int m = 0; m < 4; ++m) r[m] = (bf16_t)a[qd * 4 + m];
        *(bf16x4*)(op + dt * 32 + qd * 8 + hi * 4) = r;
      }
    }
    if (hi == 0) {
      const size_t mlb = (size_t)(kh * 16 + bh) * N_;
      lsum[mlb + nq0 + l31] = lacc;
    }
  }
}

// ---------------- kernel 5b: combine the two key-halves ----------------
__global__ __launch_bounds__(256) void k_attn_combine(const bf16_t* __restrict__ Opart,
                                                      const float* __restrict__ lsum,
                                                      bf16_t* __restrict__ att) {
  const int gid = blockIdx.x * 256 + threadIdx.x;  // 524288
  const int d8 = gid & 7;
  const int q = (gid >> 3) & (N_ - 1);
  const int bh = gid >> 15;
  const float l1 = lsum[(size_t)bh * N_ + q];
  const float l2 = lsum[(size_t)(16 + bh) * N_ + q];
  const float inv = 1.0f / (l1 + l2);
  const bf16x8 o1 = *(const bf16x8*)(Opart + ((size_t)bh * N_ + q) * HD_ + d8 * 8);
  const bf16x8 o2 = *(const bf16x8*)(Opart + ((size_t)(16 + bh) * N_ + q) * HD_ + d8 * 8);
  bf16x8 r;
#pragma unroll
  for (int j = 0; j < 8; ++j)
    r[j] = (bf16_t)(((float)o1[j] + (float)o2[j]) * inv);
  const int b = bh >> 2, hh = bh & 3;
  *(bf16x8*)(att + ((size_t)b * N_ + q) * C_ + hh * HD_ + d8 * 8) = r;
}

// ---------------- kernel 6: out-proj GEMM + bias + residual ----------------
__global__ __launch_bounds__(256) void k_gemm_out(const bf16_t* __restrict__ att,
                                                  const bf16_t* __restrict__ w2,
                                                  const float* __restrict__ out_b,
                                                  const float* __restrict__ x,
                                                  float* __restrict__ out) {
  __shared__ bf16_t As[128 * 32], Bs[128 * 32];
  const int tid = threadIdx.x, lane = tid & 63, wid = tid >> 6;
  const int g = lane >> 4, q = lane & 15;
  const int wm = wid >> 1, wn = wid & 1;
  const int m0 = blockIdx.x * 128;
  const int o0 = blockIdx.y * 128;
  f32x4 acc[4][4] = {};
  const int srow = lane >> 2, scol = (lane & 3) * 8;
  for (int kc = 0; kc < 8; ++kc) {
    const int k0 = kc * 32;
#pragma unroll
    for (int j = 0; j < 2; ++j) {
      const int chunk = wid + j * 4;
      async16(att + (size_t)(m0 + chunk * 16 + srow) * C_ + k0 + scol, &As[chunk * 512]);
      async16(w2 + (size_t)(o0 + chunk * 16 + srow) * C_ + k0 + scol, &Bs[chunk * 512]);
    }
    __syncthreads();
    bf16x8 a[4], bb[4];
#pragma unroll
    for (int t = 0; t < 4; ++t) {
      a[t] = *(const bf16x8*)&As[(wm * 64 + t * 16 + q) * 32 + g * 8];
      bb[t] = *(const bf16x8*)&Bs[(wn * 64 + t * 16 + q) * 32 + g * 8];
    }
#pragma unroll
    for (int mi = 0; mi < 4; ++mi)
#pragma unroll
      for (int ni = 0; ni < 4; ++ni)
        acc[mi][ni] = mfma_bf16(a[mi], bb[ni], acc[mi][ni]);
    __syncthreads();
  }
#pragma unroll
  for (int ni = 0; ni < 4; ++ni) {
    const int o = o0 + wn * 64 + ni * 16 + q;
    const float bias = out_b[o];
#pragma unroll
    for (int mi = 0; mi < 4; ++mi) {
      const int tokb = m0 + wm * 64 + mi * 16 + g * 4;
      const int b = tokb >> 12, n = tokb & (N_ - 1);
      const size_t idx = ((size_t)(b * C_ + o) << 12) + n;
      const float4 xv = *(const float4*)(x + idx);
      f32x4 t = acc[mi][ni];
      float4 r = make_float4(t[0] + bias + xv.x, t[1] + bias + xv.y,
                             t[2] + bias + xv.z, t[3] + bias + xv.w);
      *(float4*)(out + idx) = r;
    }
  }
}

extern "C" void kernel_launch(void* const* d_in, const int* in_sizes, int n_in,
                              void* d_out, int out_size, void* d_ws, size_t ws_size,
                              hipStream_t stream) {
  (void)in_sizes; (void)n_in; (void)out_size;
  const float* x = (const float*)d_in[0];
  const float* gn_w = (const float*)d_in[1];
  const float* gn_b = (const float*)d_in[2];
  const float* qkv_w = (const float*)d_in[3];
  const float* qkv_b = (const float*)d_in[4];
  const float* out_w = (const float*)d_in[5];
  const float* out_b = (const float*)d_in[6];
  float* out = (float*)d_out;

  char* ws = (char*)d_ws;
  float* gnscale = (float*)ws;            // 1024 f32
  float* gnshift = gnscale + 1024;        // 1024 f32
  bf16_t* w1bf = (bf16_t*)(ws + 8192);    // 196608 bf16
  bf16_t* w2bf = w1bf + 196608;           // 65536 bf16
  bf16_t* hbuf = w2bf + 65536;            // 4194304 bf16
  bf16_t* Qb = hbuf + 4194304;
  bf16_t* Kb = Qb + 4194304;
  bf16_t* Vb = Kb + 4194304;
  bf16_t* Opart = Vb + 4194304;           // 8388608 bf16 (split mode only)
  float* lsum = (float*)(Opart + 8388608);  // 131072 f32
  const size_t need = (size_t)((char*)(lsum + 131072) - ws);
  const bool split = ws_size >= need;

  k_gn_stats<<<128, 256, 0, stream>>>(x, gn_w, gn_b, gnscale, gnshift);
  k_conv_w<<<1024, 256, 0, stream>>>(qkv_w, out_w, w1bf, w2bf);
  k_gn_apply<<<512, 256, 0, stream>>>(x, gnscale, gnshift, hbuf);
  k_gemm_qkv<<<dim3(128, 6), 256, 0, stream>>>(hbuf, w1bf, qkv_b, Qb, Kb, Vb);
  if (split) {
    k_attn<2><<<512, 512, 0, stream>>>(Qb, Kb, Vb, hbuf, Opart, lsum);
    k_attn_combine<<<2048, 256, 0, stream>>>(Opart, lsum, hbuf);
  } else {
    k_attn<1><<<256, 512, 0, stream>>>(Qb, Kb, Vb, hbuf, Opart, lsum);
  }
  k_gemm_out<<<dim3(128, 2), 256, 0, stream>>>(hbuf, w2bf, out_b, x, out);
}